// Round 2
// baseline (71.748 us; speedup 1.0000x reference)
//
#include <hip/hip_runtime.h>

// Problem: ctx[b,i,d] = tanh(emb[b,i,d] * mean_j emb[b,j,d])
// B=512, I=128, D=64, fp32. Min traffic 33.5 MB -> ~5.6 us at 6.3 TB/s.
//
// R1 post-mortem: single-kernel (one block per batch, 2 blocks/CU, phase-locked
// load->barrier->store) improved only 2.1 us. Discriminating experiment: split
// into two latency-tolerant kernels through the workspace.
//   A: per-batch column means -> d_ws (read 16.8 MB, ~3 us)
//   B: pure streaming apply, 32 waves/CU, no barriers/LDS, emb re-read is
//      L3-hot from A (low FETCH_SIZE), nontemporal stores (~4 us)
// d_ws is re-poisoned by the harness each iter (the 268 MB fill) but kernel A
// fully overwrites the 128 KB we use before B reads it -> correct under poison.

#define BB 512
#define II 128
#define DD 64
#define ELEMS_PER_BATCH (II * DD)               // 8192 floats
#define VEC_PER_BATCH   (ELEMS_PER_BATCH / 4)   // 2048 float4
#define MEAN_VECS       (DD / 4)                // 16 float4 per batch

typedef float f4 __attribute__((ext_vector_type(4)));

__device__ __forceinline__ float fast_tanh(float x) {
    // tanh(x) = 1 - 2/(e^{2x}+1). v_exp_f32 + v_rcp_f32.
    float e = __expf(2.0f * x);
    return __fmaf_rn(-2.0f, __builtin_amdgcn_rcpf(e + 1.0f), 1.0f);
}

// ---------- Kernel A: means[b][d] = mean_j emb[b][j][d] ----------
// 512 blocks (one per batch) x 256 threads, 8 float4 loads per thread all in
// flight before the reduce. 2 KB LDS, one barrier, 16-lane final fold.
#define BLK_A 256
#define VPT_A (VEC_PER_BATCH / BLK_A)           // 8

__global__ __launch_bounds__(BLK_A) void mean_kernel(
        const float* __restrict__ emb, float* __restrict__ means) {
    __shared__ f4 s_part[4 * 16];               // 4 waves x 16 colgroups

    const int b = blockIdx.x;
    const int t = threadIdx.x;
    const f4* __restrict__ gin = (const f4*)(emb + (size_t)b * ELEMS_PER_BATCH);

    // j = t + 256k => j%16 == t%16: every load of this thread is colgroup t&15.
    f4 v[VPT_A];
    #pragma unroll
    for (int k = 0; k < VPT_A; ++k) v[k] = gin[t + BLK_A * k];
    f4 acc = v[0];
    #pragma unroll
    for (int k = 1; k < VPT_A; ++k) acc += v[k];

    // Lanes t, t^16, t^32, t^48 share a colgroup.
    acc.x += __shfl_xor(acc.x, 16); acc.y += __shfl_xor(acc.y, 16);
    acc.z += __shfl_xor(acc.z, 16); acc.w += __shfl_xor(acc.w, 16);
    acc.x += __shfl_xor(acc.x, 32); acc.y += __shfl_xor(acc.y, 32);
    acc.z += __shfl_xor(acc.z, 32); acc.w += __shfl_xor(acc.w, 32);

    const int lane = t & 63, wave = t >> 6;
    if (lane < 16) s_part[wave * 16 + lane] = acc;
    __syncthreads();

    if (t < 16) {
        f4 s = s_part[t] + s_part[16 + t] + s_part[32 + t] + s_part[48 + t];
        s *= (1.0f / (float)II);
        ((f4*)means)[(size_t)b * MEAN_VECS + t] = s;
    }
}

// ---------- Kernel B: out = tanh(emb * mean) ----------
// Pure streaming: 2048 blocks x 256 threads = 32 waves/CU, no LDS, no barrier.
// Each thread: 2 independent (emb, mean) load pairs hoisted, then compute+store.
#define BLK_B 256
#define GRID_B 2048
#define TOTAL_VECS (BB * VEC_PER_BATCH)         // 1,048,576 float4
#define VPT_B (TOTAL_VECS / (GRID_B * BLK_B))   // 2

__global__ __launch_bounds__(BLK_B) void apply_kernel(
        const float* __restrict__ emb, const float* __restrict__ means,
        float* __restrict__ out) {
    const f4* __restrict__ gin  = (const f4*)emb;
    const f4* __restrict__ gm   = (const f4*)means;
    f4* __restrict__       gout = (f4*)out;

    const int base = blockIdx.x * BLK_B + threadIdx.x;

    f4 x[VPT_B], m[VPT_B];
    #pragma unroll
    for (int k = 0; k < VPT_B; ++k) {
        const int v = base + k * (GRID_B * BLK_B);
        x[k] = gin[v];
        // batch = v / 2048, colgroup = v & 15
        m[k] = gm[(size_t)(v >> 11) * MEAN_VECS + (v & 15)];
    }
    #pragma unroll
    for (int k = 0; k < VPT_B; ++k) {
        const int v = base + k * (GRID_B * BLK_B);
        f4 o;
        o.x = fast_tanh(x[k].x * m[k].x);
        o.y = fast_tanh(x[k].y * m[k].y);
        o.z = fast_tanh(x[k].z * m[k].z);
        o.w = fast_tanh(x[k].w * m[k].w);
        __builtin_nontemporal_store(o, &gout[v]);
    }
}

extern "C" void kernel_launch(void* const* d_in, const int* in_sizes, int n_in,
                              void* d_out, int out_size, void* d_ws, size_t ws_size,
                              hipStream_t stream) {
    const float* emb = (const float*)d_in[0];
    float* out = (float*)d_out;
    float* means = (float*)d_ws;   // 512*64 floats = 128 KB << ws_size (268 MB)

    mean_kernel<<<dim3(BB), dim3(BLK_A), 0, stream>>>(emb, means);
    apply_kernel<<<dim3(GRID_B), dim3(BLK_B), 0, stream>>>(emb, means, out);
}

// Round 3
// 67.358 us; speedup vs baseline: 1.0652x; 1.0652x over previous
//
#include <hip/hip_runtime.h>

// Problem: ctx[b,i,d] = tanh(emb[b,i,d] * mean_j emb[b,j,d])
// B=512, I=128, D=64, fp32. Min traffic 33.5 MB -> ~5.6 us at 6.3 TB/s.
//
// Accounting (R0-R2): measured total = harness fill (~44.9 us) + fixed
// restore/launch overhead (~14 us) + kernel. R2's two-kernel split ADDED
// 5.6 us (dispatch gap ~3 us each) -> fused single kernel is right.
// R1's kernel ran ~7.6 us at only 16 waves/CU (512-thread blocks, 2/CU).
// This version: 1024-thread blocks, VPT=2 -> 2 blocks/CU = 32 waves/CU
// (100% occupancy), register-resident tile, shfl column reduce, 4.25 KB LDS,
// nontemporal stores.

#define BB 512
#define II 128
#define DD 64
#define ELEMS_PER_BATCH (II * DD)               // 8192 floats
#define VEC_PER_BATCH   (ELEMS_PER_BATCH / 4)   // 2048 float4
#define BLOCK 1024
#define VPT   (VEC_PER_BATCH / BLOCK)           // 2 float4 per thread
#define WAVES (BLOCK / 64)                      // 16

typedef float f4 __attribute__((ext_vector_type(4)));

__device__ __forceinline__ float fast_tanh(float x) {
    // tanh(x) = 1 - 2/(e^{2x}+1). v_exp_f32 + v_rcp_f32.
    // x -> +inf: e=inf, rcp=0 -> 1.  x -> -inf: e=0, rcp(1)=1 -> -1.
    float e = __expf(2.0f * x);
    return __fmaf_rn(-2.0f, __builtin_amdgcn_rcpf(e + 1.0f), 1.0f);
}

__global__ __launch_bounds__(BLOCK, 8) void ctx_tanh_kernel(
        const float* __restrict__ emb, float* __restrict__ out) {
    // One block per batch. Row = 64 floats = 16 float4; vector index j has
    // colgroup j & 15, and j = t + 1024k keeps j%16 == t%16 (k-invariant).
    __shared__ f4 s_part[WAVES * 16];   // per-(wave, colgroup) partials, 4 KB
    __shared__ f4 s_mean[16];           // 64 mean values

    const int b = blockIdx.x;
    const int t = threadIdx.x;
    const f4* __restrict__ gin  = (const f4*)(emb + (size_t)b * ELEMS_PER_BATCH);
    f4* __restrict__       gout = (f4*)(out + (size_t)b * ELEMS_PER_BATCH);

    // Phase 1: both loads in flight, tile stays in registers.
    f4 v[VPT];
    #pragma unroll
    for (int k = 0; k < VPT; ++k) v[k] = gin[t + BLOCK * k];

    f4 acc = v[0];
    #pragma unroll
    for (int k = 1; k < VPT; ++k) acc += v[k];

    // In-wave column reduce: lanes t, t^16, t^32, t^48 share colgroup t&15.
    acc.x += __shfl_xor(acc.x, 16); acc.y += __shfl_xor(acc.y, 16);
    acc.z += __shfl_xor(acc.z, 16); acc.w += __shfl_xor(acc.w, 16);
    acc.x += __shfl_xor(acc.x, 32); acc.y += __shfl_xor(acc.y, 32);
    acc.z += __shfl_xor(acc.z, 32); acc.w += __shfl_xor(acc.w, 32);

    const int lane = t & 63;
    const int wave = t >> 6;
    if (lane < 16) s_part[wave * 16 + lane] = acc;
    __syncthreads();

    // Phase 2: one wave folds the 16 wave-partials per colgroup.
    // Lane layout: g = lane&15 (colgroup), slot = lane>>4 in [0,4): each lane
    // sums waves {slot, slot+4, slot+8, slot+12}, then shfl folds the 4 slots.
    if (t < 64) {
        const int g = t & 15, slot = t >> 4;
        f4 s = s_part[(slot     ) * 16 + g] + s_part[(slot +  4) * 16 + g]
             + s_part[(slot + 8) * 16 + g] + s_part[(slot + 12) * 16 + g];
        s.x += __shfl_xor(s.x, 16); s.y += __shfl_xor(s.y, 16);
        s.z += __shfl_xor(s.z, 16); s.w += __shfl_xor(s.w, 16);
        s.x += __shfl_xor(s.x, 32); s.y += __shfl_xor(s.y, 32);
        s.z += __shfl_xor(s.z, 32); s.w += __shfl_xor(s.w, 32);
        if (t < 16) {
            s *= (1.0f / (float)II);
            s_mean[t] = s;
        }
    }
    __syncthreads();

    // Phase 3: scale + tanh from registers, nontemporal coalesced stores
    // (output written once, never re-read by us -> don't pollute L2).
    const f4 m4 = s_mean[t & 15];
    #pragma unroll
    for (int k = 0; k < VPT; ++k) {
        f4 o;
        o.x = fast_tanh(v[k].x * m4.x);
        o.y = fast_tanh(v[k].y * m4.y);
        o.z = fast_tanh(v[k].z * m4.z);
        o.w = fast_tanh(v[k].w * m4.w);
        __builtin_nontemporal_store(o, &gout[t + BLOCK * k]);
    }
}

extern "C" void kernel_launch(void* const* d_in, const int* in_sizes, int n_in,
                              void* d_out, int out_size, void* d_ws, size_t ws_size,
                              hipStream_t stream) {
    const float* emb = (const float*)d_in[0];
    float* out = (float*)d_out;
    ctx_tanh_kernel<<<dim3(BB), dim3(BLOCK), 0, stream>>>(emb, out);
}

// Round 4
// 66.810 us; speedup vs baseline: 1.0739x; 1.0082x over previous
//
#include <hip/hip_runtime.h>

// Problem: ctx[b,i,d] = tanh(emb[b,i,d] * mean_j emb[b,j,d])
// B=512, I=128, D=64, fp32. Min traffic 33.5 MB -> ~5.6 us at 6.3 TB/s.
//
// Accounting (R0-R3): measured total = harness ws-fill (~44.8 us, fixed) +
// restore/gap overhead (~14 us, fixed) + kernel. Best shape so far: 512-thr
// blocks (R1, 66.1 us total). 1024-thr (R3) regressed: barrier spans 16 waves.
// This version keeps R1's shape but removes the SECOND barrier + serial
// phase-2: after the in-wave shfl fold, each thread sums its colgroup's 8
// wave-partials straight from LDS (8 ds_read_b128, 2-way bank aliasing = free).
// One barrier total, tile in registers, nontemporal stores.

#define BB 512
#define II 128
#define DD 64
#define ELEMS_PER_BATCH (II * DD)               // 8192 floats
#define VEC_PER_BATCH   (ELEMS_PER_BATCH / 4)   // 2048 float4
#define BLOCK 512
#define VPT   (VEC_PER_BATCH / BLOCK)           // 4 float4 per thread
#define WAVES (BLOCK / 64)                      // 8

typedef float f4 __attribute__((ext_vector_type(4)));

__device__ __forceinline__ float fast_tanh(float x) {
    // tanh(x) = 1 - 2/(e^{2x}+1). v_exp_f32 + v_rcp_f32.
    // x -> +inf: e=inf, rcp=0 -> 1.  x -> -inf: e=0, rcp(1)=1 -> -1.
    float e = __expf(2.0f * x);
    return __fmaf_rn(-2.0f, __builtin_amdgcn_rcpf(e + 1.0f), 1.0f);
}

__global__ __launch_bounds__(BLOCK, 4) void ctx_tanh_kernel(
        const float* __restrict__ emb, float* __restrict__ out) {
    // One block per batch. Row = 64 floats = 16 float4; vector index j has
    // colgroup j & 15, and j = t + 512k keeps j%16 == t%16 (k-invariant).
    __shared__ f4 s_part[WAVES * 16];   // per-(wave, colgroup) partials, 2 KB

    const int b = blockIdx.x;
    const int t = threadIdx.x;
    const f4* __restrict__ gin  = (const f4*)(emb + (size_t)b * ELEMS_PER_BATCH);
    f4* __restrict__       gout = (f4*)(out + (size_t)b * ELEMS_PER_BATCH);

    // Phase 1: all 4 loads in flight, tile stays in registers.
    f4 v[VPT];
    #pragma unroll
    for (int k = 0; k < VPT; ++k) v[k] = gin[t + BLOCK * k];

    f4 acc = v[0];
    #pragma unroll
    for (int k = 1; k < VPT; ++k) acc += v[k];

    // In-wave column reduce: lanes t, t^16, t^32, t^48 share colgroup t&15.
    acc.x += __shfl_xor(acc.x, 16); acc.y += __shfl_xor(acc.y, 16);
    acc.z += __shfl_xor(acc.z, 16); acc.w += __shfl_xor(acc.w, 16);
    acc.x += __shfl_xor(acc.x, 32); acc.y += __shfl_xor(acc.y, 32);
    acc.z += __shfl_xor(acc.z, 32); acc.w += __shfl_xor(acc.w, 32);

    const int lane = t & 63;
    const int wave = t >> 6;
    if (lane < 16) s_part[wave * 16 + lane] = acc;
    __syncthreads();   // the ONLY barrier

    // Phase 2+3 fused: every thread folds its colgroup's 8 wave-partials
    // (per wave-quarter: 16 distinct f4 addrs -> 2-way bank aliasing, free),
    // then applies mean-scale + tanh from registers and streams out.
    const int g = t & 15;
    f4 m4 = s_part[g];
    #pragma unroll
    for (int w = 1; w < WAVES; ++w) m4 += s_part[w * 16 + g];
    m4 *= (1.0f / (float)II);

    #pragma unroll
    for (int k = 0; k < VPT; ++k) {
        f4 o;
        o.x = fast_tanh(v[k].x * m4.x);
        o.y = fast_tanh(v[k].y * m4.y);
        o.z = fast_tanh(v[k].z * m4.z);
        o.w = fast_tanh(v[k].w * m4.w);
        __builtin_nontemporal_store(o, &gout[t + BLOCK * k]);
    }
}

extern "C" void kernel_launch(void* const* d_in, const int* in_sizes, int n_in,
                              void* d_out, int out_size, void* d_ws, size_t ws_size,
                              hipStream_t stream) {
    const float* emb = (const float*)d_in[0];
    float* out = (float*)d_out;
    ctx_tanh_kernel<<<dim3(BB), dim3(BLOCK), 0, stream>>>(emb, out);
}